// Round 2
// baseline (16147.987 us; speedup 1.0000x reference)
//
#include <hip/hip_runtime.h>

// FPS: 2 batches x 131072 pts, 4096 samples/batch, seed = point 0.
// Barrier-free persistent kernel. Every WAVE is an independent agent:
//   update reg-resident dists -> 64-lane u64 butterfly argmax ->
//   lane0 relaxed agent-scope store of self-validating key ->
//   all lanes poll the 128 per-wave slots (2 each) until step tags match ->
//   butterfly over slot keys -> winner idx -> cached broadcast load of coords.
// No __syncthreads, no fences, no LDS in the main loop.
// Key = dist_bits<<32 | step<<17 | (0x1FFFF - idx): u64 max == lexicographic
// (dist desc, idx asc) == jnp.argmax first-index tiebreak. Exact fp32
// (contract off, __fmul_rn/__fadd_rn) matches the numpy reference bitwise.
//
// Safety of relaxed+tagged ring (RING=4): a wave stores its step-s key
// BEFORE polling step s; advancing to store step s+1 requires seeing every
// wave's step-s key. Hence no wave's stores lead the slowest poller by >1
// step, so a ring position (reused every 4 steps) can never be overwritten
// while any wave still needs it. Zeroed slots (memset) never match a tag
// since steps start at 1.

#define NB    32      // blocks per batch
#define TPB   256     // threads per block (4 waves, 1 wave/SIMD)
#define PPT   16      // points per thread: NB*TPB*PPT = 131072
#define NPB   131072
#define MSAMP 4096
#define RING  4
#define NW    (NB * 4)  // per-wave slots per batch = 128

typedef unsigned long long u64;

__global__ __launch_bounds__(TPB, 1)
void fps_kernel(const float4* __restrict__ pts, float* __restrict__ out,
                u64* __restrict__ slots)
{
#pragma clang fp contract(off)
  const int batch = blockIdx.x >> 5;         // / NB
  const int blk   = blockIdx.x & (NB - 1);
  const int tid   = threadIdx.x;
  const int lane  = tid & 63;
  const int wv    = tid >> 6;                // 0..3
  const int gw    = (blk << 2) | wv;         // wave id within batch [0,128)
  const float4* bpts = pts + (size_t)batch * NPB;
  u64* bslots = slots + (size_t)batch * (RING * NW);

  const int base = blk * (TPB * PPT);

  // Register-resident coords + running min-dists (64 VGPRs of state).
  float px[PPT], py[PPT], pz[PPT], dist[PPT];
#pragma unroll
  for (int k = 0; k < PPT; ++k) {
    float4 p = bpts[base + k * TPB + tid];   // row = (b, x, y, z)
    px[k] = p.y; py[k] = p.z; pz[k] = p.w;
    dist[k] = __builtin_inff();              // min(inf, d) == d bit-exactly
  }

  float4 seed = bpts[0];                     // broadcast load, all lanes
  float sx = seed.y, sy = seed.z, sz = seed.w;
  if (blk == 0 && wv == 0 && lane == 0) {
    float4 o; o.x = (float)batch; o.y = sx; o.z = sy; o.w = sz;
    *(float4*)(out + (size_t)batch * MSAMP * 4) = o;   // output row 0 = seed
  }

  for (int s = 1; s < MSAMP; ++s) {
    // ---- fused dist update + per-thread argmax (exact fp32) ----
    float bestd = -1.0f; int besti = 0;
#pragma unroll
    for (int k = 0; k < PPT; ++k) {
      float dx = px[k] - sx, dy = py[k] - sy, dz = pz[k] - sz;
      float d2 = __fadd_rn(__fadd_rn(__fmul_rn(dx, dx), __fmul_rn(dy, dy)),
                           __fmul_rn(dz, dz));
      float nd = fminf(dist[k], d2);
      dist[k] = nd;
      // idx ascends with k => strict '>' keeps first max (jnp.argmax rule)
      if (nd > bestd) { bestd = nd; besti = base + k * TPB + tid; }
    }

    // Self-validating key: dist | step-tag | inverted idx.
    u64 pv = ((u64)__float_as_uint(bestd) << 32) | ((u64)s << 17) |
             (u64)(0x1FFFF - besti);

    // ---- wave argmax (butterfly over 64 lanes) ----
#pragma unroll
    for (int m = 32; m >= 1; m >>= 1) {
      u64 o = __shfl_xor(pv, m, 64);
      if (o > pv) pv = o;
    }

    u64* ring = bslots + (size_t)(s & (RING - 1)) * NW;
    if (lane == 0)
      __hip_atomic_store(&ring[gw], pv, __ATOMIC_RELAXED,
                         __HIP_MEMORY_SCOPE_AGENT);

    // ---- poll all NW slots: lane L owns slots L and L+64 ----
    const u64* p0 = &ring[lane];
    const u64* p1 = &ring[64 + lane];
    u64 k0, k1; bool ok;
    do {
      k0 = __hip_atomic_load(p0, __ATOMIC_RELAXED, __HIP_MEMORY_SCOPE_AGENT);
      k1 = __hip_atomic_load(p1, __ATOMIC_RELAXED, __HIP_MEMORY_SCOPE_AGENT);
      ok = (((k0 >> 17) & 0x7FFF) == (u64)s) &&
           (((k1 >> 17) & 0x7FFF) == (u64)s);
    } while (!ok);

    // ---- cross-wave argmax over the 128 keys ----
    u64 w = k0 > k1 ? k0 : k1;
#pragma unroll
    for (int m = 32; m >= 1; m >>= 1) {
      u64 o = __shfl_xor(w, m, 64);
      if (o > w) w = o;
    }

    // Winner coords from the IMMUTABLE input array: plain cached broadcast
    // load (no coherence needed — pts is never written).
    int widx = 0x1FFFF - (int)(w & 0x1FFFF);
    float4 c = bpts[widx];
    sx = c.y; sy = c.z; sz = c.w;

    if (blk == 0 && wv == 0 && lane == 0) {
      float4 o; o.x = (float)batch; o.y = sx; o.z = sy; o.w = sz;
      *(float4*)(out + (size_t)(batch * MSAMP + s) * 4) = o;
    }
  }
}

extern "C" void kernel_launch(void* const* d_in, const int* in_sizes, int n_in,
                              void* d_out, int out_size, void* d_ws, size_t ws_size,
                              hipStream_t stream) {
  const float4* pts = (const float4*)d_in[0];
  float* out = (float*)d_out;
  u64* slots = (u64*)d_ws;

  // Zero the slot rings (8 KB) so poisoned tags can never validate.
  hipMemsetAsync(d_ws, 0, (size_t)2 * RING * NW * sizeof(u64), stream);

  dim3 grid(2 * NB), block(TPB);
  hipLaunchKernelGGL(fps_kernel, grid, block, 0, stream, pts, out, slots);
}

// Round 3
// 10592.175 us; speedup vs baseline: 1.5245x; 1.5245x over previous
//
#include <hip/hip_runtime.h>

// FPS: 2 batches x 131072 pts, 4096 samples/batch, seed = point 0.
// Persistent kernel, register-resident coords+dists. Per step:
//   fused dist-update + thread argmax -> 64-lane u64 butterfly ->
//   LDS 4-way block reduce (ONE barrier) -> wave0 lanes 0..1 store a 32B
//   slot {key | coords}, two self-validating 16B quads (tag embedded in
//   both) with global_store_dwordx4 sc0 sc1 -> ALL waves poll: one
//   global_load_dwordx4 sc0 sc1 per lane covers all 64 quads ->
//   butterfly over keys -> winner coords extracted via ballot+shfl
//   (NO dependent global coord load, no acquire/release cache ops).
// Key = dist_bits<<32 | step<<17 | (0x1FFFF - idx): u64 max ==
// (dist desc, idx asc) == jnp.argmax first-index tiebreak. Exact fp32.
//
// Ring safety (RING=4): a block stores step s+1 only after ALL its waves
// passed the step-s poll (barrier gates the storer on every sibling), and
// any block storing s+2 requires every block stored s+1. So no store can
// lead the slowest poller by more than 1 ring position; reuse distance 4.
// Poisoned (0xAA) or zeroed slots never tag-match (s in 1..4095).

#define NB    32      // blocks per batch
#define TPB   256     // 4 waves
#define PPT   16      // 32*256*16 = 131072
#define NPB   131072
#define MSAMP 4096
#define RING  4

typedef unsigned long long u64;
typedef unsigned int u32;
typedef __attribute__((ext_vector_type(4))) u32 u32x4;

__device__ __forceinline__ u32x4 ld16_sc(const u32* p) {
  u32x4 r;
  asm volatile("global_load_dwordx4 %0, %1, off sc0 sc1\n\t"
               "s_waitcnt vmcnt(0)"
               : "=v"(r) : "v"(p) : "memory");
  return r;
}
__device__ __forceinline__ void st16_sc(u32* p, u32x4 v) {
  asm volatile("global_store_dwordx4 %0, %1, off sc0 sc1\n\t"
               "s_waitcnt vmcnt(0)"
               :: "v"(p), "v"(v) : "memory");
}

__global__ __launch_bounds__(TPB, 1)
void fps_kernel(const float4* __restrict__ pts, float* __restrict__ out,
                u32* __restrict__ slots)
{
#pragma clang fp contract(off)
  const int batch = blockIdx.x >> 5;
  const int blk   = blockIdx.x & (NB - 1);
  const int tid   = threadIdx.x;
  const int lane  = tid & 63;
  const int wv    = tid >> 6;
  const float4* bpts = pts + (size_t)batch * NPB;
  u32* bslots = slots + (size_t)batch * (RING * NB * 8);  // 8 u32 per slot

  __shared__ u64   s_key[4];
  __shared__ float s_cx[4], s_cy[4], s_cz[4];

  const int base = blk * (TPB * PPT);

  float px[PPT], py[PPT], pz[PPT], dist[PPT];
#pragma unroll
  for (int k = 0; k < PPT; ++k) {
    float4 p = bpts[base + k * TPB + tid];   // row = (b, x, y, z)
    px[k] = p.y; py[k] = p.z; pz[k] = p.w;
    dist[k] = __builtin_inff();              // min(inf, d) == d bit-exactly
  }

  float4 seed = bpts[0];
  float sx = seed.y, sy = seed.z, sz = seed.w;
  if (blk == 0 && wv == 0 && lane == 0) {
    float4 o; o.x = (float)batch; o.y = sx; o.z = sy; o.w = sz;
    *(float4*)(out + (size_t)batch * MSAMP * 4) = o;
  }

  for (int s = 1; s < MSAMP; ++s) {
    // ---- fused dist update + per-thread argmax, coords tracked ----
    float bestd = -1.0f, bx = 0.f, by = 0.f, bz = 0.f; int besti = 0;
#pragma unroll
    for (int k = 0; k < PPT; ++k) {
      float dx = px[k] - sx, dy = py[k] - sy, dz = pz[k] - sz;
      float d2 = __fadd_rn(__fadd_rn(__fmul_rn(dx, dx), __fmul_rn(dy, dy)),
                           __fmul_rn(dz, dz));
      float nd = fminf(dist[k], d2);
      dist[k] = nd;
      if (nd > bestd) {                      // strict '>': first-index tiebreak
        bestd = nd; besti = base + k * TPB + tid;
        bx = px[k]; by = py[k]; bz = pz[k];
      }
    }

    u64 pv0 = ((u64)__float_as_uint(bestd) << 32) | ((u64)s << 17) |
              (u64)(0x1FFFF - besti);
    u64 pv = pv0;
#pragma unroll
    for (int m = 32; m >= 1; m >>= 1) {
      u64 o = __shfl_xor(pv, m, 64);
      if (o > pv) pv = o;
    }
    // winner lane of this wave (keys unique: idx embedded)
    int wl = __ffsll(__ballot(pv0 == pv)) - 1;
    float wx = __shfl(bx, wl, 64), wy = __shfl(by, wl, 64),
          wz = __shfl(bz, wl, 64);
    if (lane == 0) { s_key[wv] = pv; s_cx[wv] = wx; s_cy[wv] = wy; s_cz[wv] = wz; }
    __syncthreads();                         // the ONE barrier per step

    u32* ring = bslots + (size_t)(s & (RING - 1)) * (NB * 8);
    if (wv == 0 && lane < 2) {
      // 4-way block reduce from LDS (redundant across lanes 0..1)
      u64 k0 = s_key[0], k1 = s_key[1], k2 = s_key[2], k3 = s_key[3];
      int bi = 0; u64 bk = k0;
      if (k1 > bk) { bk = k1; bi = 1; }
      if (k2 > bk) { bk = k2; bi = 2; }
      if (k3 > bk) { bk = k3; bi = 3; }
      u32x4 q;
      if (lane == 0) {                       // quad0: key + x,y (tag in key)
        q.x = (u32)(bk & 0xFFFFFFFFull); q.y = (u32)(bk >> 32);
        q.z = __float_as_uint(s_cx[bi]);  q.w = __float_as_uint(s_cy[bi]);
      } else {                               // quad1: tag + z
        q.x = (u32)s; q.y = __float_as_uint(s_cz[bi]); q.z = 0u; q.w = 0u;
      }
      st16_sc(ring + blk * 8 + lane * 4, q);
    }

    // ---- poll: lane L loads quad L (slot L>>1, half L&1), 1 instr/iter ----
    const u32* pp = ring + lane * 4;
    u32x4 q;
    for (;;) {
      q = ld16_sc(pp);
      bool ok = ((lane & 1) == 0) ? ((q.x >> 17) == (u32)s) : (q.x == (u32)s);
      if (__ballot(ok) == ~0ull) break;
      __builtin_amdgcn_s_sleep(1);           // backoff: keep fabric calm
    }

    // ---- cross-block argmax + register-resident coord extraction ----
    u64 key = ((lane & 1) == 0) ? (((u64)q.y << 32) | (u64)q.x) : 0ull;
    u64 w = key;
#pragma unroll
    for (int m = 32; m >= 1; m >>= 1) {
      u64 o = __shfl_xor(w, m, 64);
      if (o > w) w = o;
    }
    int wl2 = __ffsll(__ballot(key == w && ((lane & 1) == 0))) - 1;
    sx = __shfl(__uint_as_float(q.z), wl2, 64);      // x from quad0 lane
    sy = __shfl(__uint_as_float(q.w), wl2, 64);      // y from quad0 lane
    sz = __shfl(__uint_as_float(q.y), wl2 + 1, 64);  // z from quad1 lane

    if (blk == 0 && wv == 0 && lane == 0) {
      float4 o; o.x = (float)batch; o.y = sx; o.z = sy; o.w = sz;
      *(float4*)(out + (size_t)(batch * MSAMP + s) * 4) = o;
    }
  }
}

extern "C" void kernel_launch(void* const* d_in, const int* in_sizes, int n_in,
                              void* d_out, int out_size, void* d_ws, size_t ws_size,
                              hipStream_t stream) {
  const float4* pts = (const float4*)d_in[0];
  float* out = (float*)d_out;
  u32* slots = (u32*)d_ws;

  // Zero both batches' slot rings (8 KB): stale tags can never validate.
  hipMemsetAsync(d_ws, 0, (size_t)2 * RING * NB * 32, stream);

  dim3 grid(2 * NB), block(TPB);
  hipLaunchKernelGGL(fps_kernel, grid, block, 0, stream, pts, out, slots);
}